// Round 8
// baseline (470.461 us; speedup 1.0000x reference)
//
#include <hip/hip_runtime.h>
#include <math.h>

#define NT 256           // 4 waves per block
#define QW 16            // queries per wave
#define WPB 4            // waves per block
#define MTOT 131072
#define IMG_H 384
#define IMG_W 512
#define H8 48
#define W8 64
#define H16 24
#define W16 32

typedef _Float16 half8_t __attribute__((ext_vector_type(8)));
typedef float f32x4_t __attribute__((ext_vector_type(4)));
typedef float f32x2_t __attribute__((ext_vector_type(2)));
typedef unsigned short u16;

// packed weight bases (in halfs) -- fragment order: ((nt*KT + kt)*64 + lane)*8 + j
// k = kt*32 + (lane>>4)*8 + j (plain); columns PERMUTED: physical slot n holds
// logical col c(n) = (n&~31) | (((n>>2)&3)<<3) | (((n>>4)&1)<<2) | (n&3)
// so that the D-register layout == next GEMM's A-fragment layout (no shuffle).
#define PW_PP1    0
#define PW_PP2    12288
#define PW_P8CAT  28672
#define PW_P16CAT 61440
#define PW_F1W1   94208
#define PW_F1W2   126976
#define PW_F2W1   159744
#define PW_F2W2   192512
#define PW_HW1    225280
#define PW_HW2    245760
#define PW_END    253952
#define FT8_OFF   PW_END
#define FT8_CNT   (2*H8*W8*128)
#define FT16_OFF  (FT8_OFF + FT8_CNT)
#define FT16_CNT  (2*H16*W16*128)
#define FB_OFF    (FT16_OFF + FT16_CNT)   // 256 floats (fused biases), 16B aligned

__device__ __forceinline__ u16 tohalf(float v) {
  return __builtin_bit_cast(u16, (_Float16)v);
}
// tanh-form gelu: x * sigmoid(1.5957691x + 0.07135482x^3); |err vs exact erf-gelu| < 3e-3
__device__ __forceinline__ float geluf(float x) {
  float x2 = x * x;
  float t = x * fmaf(x2, 0.0713548162726f, 1.5957691216057308f);
  float e = __expf(-t);
  return x * __builtin_amdgcn_rcpf(1.0f + e);
}

// bilinear on a single [Hd][Wd] f32 plane, align_corners=True + border clamp
__device__ __forceinline__ float bilin_plane(const float* __restrict__ plane,
                                             int Wd, int Hd, float x, float y) {
  x = fminf(fmaxf(x, 0.f), (float)(Wd - 1));
  y = fminf(fmaxf(y, 0.f), (float)(Hd - 1));
  float x0f = floorf(x), y0f = floorf(y);
  int x0 = (int)x0f, y0 = (int)y0f;
  int x1 = min(x0 + 1, Wd - 1), y1 = min(y0 + 1, Hd - 1);
  float wx = x - x0f, wy = y - y0f;
  const float* r0 = plane + y0 * Wd;
  const float* r1 = plane + y1 * Wd;
  float v00 = r0[x0], v01 = r0[x1], v10 = r1[x0], v11 = r1[x1];
  float top = v00 + wx * (v01 - v00);
  float bot = v10 + wx * (v11 - v10);
  return top + wy * (bot - top);
}

// bilinear gather of 8 consecutive fp16 channels from channel-last [Hd][Wd][128]
__device__ __forceinline__ half8_t sample_feat8(const u16* __restrict__ ft, int Wd, int Hd,
                                                float x, float y, int ch0) {
  x = fminf(fmaxf(x, 0.f), (float)(Wd - 1));
  y = fminf(fmaxf(y, 0.f), (float)(Hd - 1));
  float x0f = floorf(x), y0f = floorf(y);
  int x0 = (int)x0f, y0 = (int)y0f;
  int x1 = min(x0 + 1, Wd - 1), y1 = min(y0 + 1, Hd - 1);
  float wx = x - x0f, wy = y - y0f;
  half8_t v00 = *reinterpret_cast<const half8_t*>(ft + (y0 * Wd + x0) * 128 + ch0);
  half8_t v01 = *reinterpret_cast<const half8_t*>(ft + (y0 * Wd + x1) * 128 + ch0);
  half8_t v10 = *reinterpret_cast<const half8_t*>(ft + (y1 * Wd + x0) * 128 + ch0);
  half8_t v11 = *reinterpret_cast<const half8_t*>(ft + (y1 * Wd + x1) * 128 + ch0);
  half8_t r;
#pragma unroll
  for (int j = 0; j < 8; ++j) {
    float top = (float)v00[j] + wx * ((float)v01[j] - (float)v00[j]);
    float bot = (float)v10[j] + wx * ((float)v11[j] - (float)v10[j]);
    r[j] = (_Float16)(top + wy * (bot - top));
  }
  return r;
}

// 8 patch-pixel values for logical cols c0..c0+7 (c = 3p+ch, kxk=5x5 RGB)
__device__ __forceinline__ half8_t sample_patch8(const float* __restrict__ imgb,
                                                 float qx, float qy, int c0) {
  half8_t o;
#pragma unroll
  for (int j = 0; j < 8; ++j) {
    int c = c0 + j;
    float v = 0.f;
    if (c < 75) {
      int p = c / 3, ch = c - p * 3;
      int iy = p / 5, ix = p - iy * 5;
      v = bilin_plane(imgb + ch * (IMG_H * IMG_W), IMG_W, IMG_H,
                      qx + (float)(ix - 2), qy + (float)(iy - 2));
    }
    o[j] = (_Float16)v;
  }
  return o;
}

// pe fragment: logical cols 128+8g+j of mi = [h|local(2)|enc(24)|coarse(2)|0..]
__device__ __forceinline__ half8_t pe_frag(float qx, float qy, float cv0, float cv1, int g) {
  float qx8 = qx * 0.125f, qy8 = qy * 0.125f;
  float lx = (qx8 - rintf(qx8)) * 2.f, ly = (qy8 - rintf(qy8)) * 2.f;
  half8_t o;
#pragma unroll
  for (int j = 0; j < 8; ++j) {
    int idx = 8 * g + j;
    float val = 0.f;
    if (idx < 2) val = idx ? ly : lx;
    else if (idx < 26) {
      int k = idx - 2;
      int dim = k / 12, tt = k - dim * 12;
      int band = tt % 6, iscos = tt / 6;
      float loc = dim ? ly : lx;
      float ang = loc * 3.14159265358979323846f * (float)(1 << band);
      val = iscos ? __cosf(ang) : __sinf(ang);
    } else if (idx == 26) val = cv0;
    else if (idx == 27) val = cv1;
    o[j] = (_Float16)val;
  }
  return o;
}

// register GEMM: 16 rows (q=l15) x N16*16 cols, K = KT*32; af in regs, bf from L2
template <int N16, int KT>
__device__ __forceinline__ void gemm_acc(const u16* __restrict__ wpk,
                                         const half8_t* af, int lane, f32x4_t* acc) {
#pragma unroll
  for (int n = 0; n < N16; ++n) acc[n] = (f32x4_t){0.f, 0.f, 0.f, 0.f};
#pragma unroll
  for (int kt = 0; kt < KT; ++kt) {
#pragma unroll
    for (int n = 0; n < N16; ++n) {
      half8_t bf = *reinterpret_cast<const half8_t*>(wpk + ((n * KT + kt) * 64 + lane) * 8);
      acc[n] = __builtin_amdgcn_mfma_f32_16x16x32_f16(bf, af[kt], acc[n], 0, 0, 0);
    }
  }
}

// epilogue: bias (+gelu) and repack acc -> af fragments (logical col = 32n2+8g+{0..7})
template <int N16, int ACT>
__device__ __forceinline__ void epi_af(const f32x4_t* acc, const float* __restrict__ bias,
                                       int g, half8_t* outf) {
#pragma unroll
  for (int n2 = 0; n2 < N16 / 2; ++n2) {
    const int cb = 32 * n2 + 8 * g;
    f32x4_t bv0 = *reinterpret_cast<const f32x4_t*>(bias + cb);
    f32x4_t bv1 = *reinterpret_cast<const f32x4_t*>(bias + cb + 4);
    half8_t o;
#pragma unroll
    for (int r = 0; r < 4; ++r) {
      float v0 = acc[2 * n2][r] + bv0[r];
      float v1 = acc[2 * n2 + 1][r] + bv1[r];
      if (ACT) { v0 = geluf(v0); v1 = geluf(v1); }
      o[r] = (_Float16)v0;
      o[4 + r] = (_Float16)v1;
    }
    outf[n2] = o;
  }
}

// epilogue with fused LayerNorm (128 cols): reduce over lane's 32 vals + shfl over g
__device__ __forceinline__ void epi_ln(const f32x4_t* acc, const float* __restrict__ bias,
                                       const float* __restrict__ lw,
                                       const float* __restrict__ lb,
                                       int g, half8_t* outf) {
  float x[32];
  float s = 0.f, s2 = 0.f;
#pragma unroll
  for (int n = 0; n < 8; ++n) {
    const int cb = 32 * (n >> 1) + 8 * g + 4 * (n & 1);
    f32x4_t bv = *reinterpret_cast<const f32x4_t*>(bias + cb);
#pragma unroll
    for (int r = 0; r < 4; ++r) {
      float v = acc[n][r] + bv[r];
      x[n * 4 + r] = v; s += v; s2 += v * v;
    }
  }
  s += __shfl_xor(s, 16); s2 += __shfl_xor(s2, 16);
  s += __shfl_xor(s, 32); s2 += __shfl_xor(s2, 32);
  const float mean = s * 0.0078125f;
  const float rstd = rsqrtf(s2 * 0.0078125f - mean * mean + 1e-5f);
#pragma unroll
  for (int n2 = 0; n2 < 4; ++n2) {
    half8_t o;
#pragma unroll
    for (int h = 0; h < 2; ++h) {
      const int cb = 32 * n2 + 8 * g + 4 * h;
      f32x4_t wv = *reinterpret_cast<const f32x4_t*>(lw + cb);
      f32x4_t bb = *reinterpret_cast<const f32x4_t*>(lb + cb);
#pragma unroll
      for (int r = 0; r < 4; ++r)
        o[4 * h + r] = (_Float16)((x[(2 * n2 + h) * 4 + r] - mean) * rstd * wv[r] + bb[r]);
    }
    outf[n2] = o;
  }
}

// ---------------- prep kernels ----------------
struct PackArgs {
  const float *pp_w1, *pp_w2, *p8_w, *f1_ph_w, *f1_gate, *p16_w, *f2_ph_w, *f2_gate;
  const float *f1_w1, *f1_w2, *f2_w1, *f2_w2, *h_w1, *h_w2;
  u16* dst;
};

__global__ void pack_weights(PackArgs a) {
  const int KTs[10]   = {3, 4, 8, 8, 4, 8, 4, 8, 5, 4};
  const int Ks[10]    = {75, 128, 256, 256, 128, 256, 128, 256, 156, 128};
  const int bases[11] = {0, 12288, 28672, 61440, 94208, 126976,
                         159744, 192512, 225280, 245760, 253952};
  int stride = gridDim.x * blockDim.x;
  for (int i = blockIdx.x * blockDim.x + threadIdx.x; i < PW_END; i += stride) {
    int s = 0;
    while (i >= bases[s + 1]) ++s;
    int rem = i - bases[s];
    int e = rem & 511, lane = e >> 3, j = e & 7;
    int ntkt = rem >> 9;
    int kt = ntkt % KTs[s], nt = ntkt / KTs[s];
    int k = kt * 32 + ((lane >> 4) << 3) + j;
    int pcol = (nt << 4) + (lane & 15);
    // column permutation: physical slot -> logical column (bit-field swap in 32-group)
    int col = (pcol & ~31) | (((pcol >> 2) & 3) << 3) | (((pcol >> 4) & 1) << 2) | (pcol & 3);
    float v = 0.f;
    if (k < Ks[s]) {
      switch (s) {
        case 0: v = a.pp_w1[k * 128 + col]; break;
        case 1: v = a.pp_w2[k * 128 + col]; break;
        case 2: v = (k < 128) ? a.p8_w[k * 128 + col]
                              : a.f1_ph_w[(k - 128) * 128 + col] /
                                    (1.f + expf(-a.f1_gate[col])); break;
        case 3: v = (k < 128) ? a.p16_w[k * 128 + col]
                              : a.f2_ph_w[(k - 128) * 128 + col] /
                                    (1.f + expf(-a.f2_gate[col])); break;
        case 4: v = a.f1_w1[k * 256 + col]; break;
        case 5: v = a.f1_w2[k * 128 + col]; break;
        case 6: v = a.f2_w1[k * 256 + col]; break;
        case 7: v = a.f2_w2[k * 128 + col]; break;
        case 8: v = a.h_w1[k * 128 + col]; break;
        case 9: v = a.h_w2[k * 64 + col]; break;
      }
    }
    a.dst[i] = tohalf(v);
  }
}

__global__ void fuse_bias(const float* __restrict__ p8_b, const float* __restrict__ f1_ph_b,
                          const float* __restrict__ f1_gate,
                          const float* __restrict__ p16_b, const float* __restrict__ f2_ph_b,
                          const float* __restrict__ f2_gate, float* __restrict__ fb) {
  int t = threadIdx.x;
  if (t < 128) {
    fb[t] = p8_b[t] + f1_ph_b[t] / (1.f + expf(-f1_gate[t]));
    fb[128 + t] = p16_b[t] + f2_ph_b[t] / (1.f + expf(-f2_gate[t]));
  }
}

__global__ void cvt_cl_f16(const float* __restrict__ src, u16* __restrict__ dst,
                           int Hd, int Wd) {
  int total = 2 * 128 * Hd * Wd;
  int stride = gridDim.x * blockDim.x;
  for (int i = blockIdx.x * blockDim.x + threadIdx.x; i < total; i += stride) {
    int x = i % Wd;
    int t = i / Wd;
    int y = t % Hd; t /= Hd;
    int c = t % 128;
    int b = t / 128;
    dst[((b * Hd + y) * Wd + x) * 128 + c] = tohalf(src[i]);
  }
}

// ---------------- main fused kernel (fully register-resident, no LDS, no barriers) ----------------
struct KParams {
  const float *img, *coarse_flow, *qc;
  const u16 *wpk, *ft8, *ft16;
  const float *fb;
  const float *pp_b1, *pp_b2;
  const float *f1_b1, *f1_b2, *f1_ln_w, *f1_ln_b;
  const float *f2_b1, *f2_b2, *f2_ln_w, *f2_ln_b;
  const float *h_b1, *h_b2, *h_w3, *h_b3;
  float* out;
};

__global__ __launch_bounds__(NT, 3) void ifd_reg(KParams P) {
  const int tid = threadIdx.x;
  const int lane = tid & 63;
  const int l15 = lane & 15;
  const int g = lane >> 4;
  const int m0 = (blockIdx.x * WPB + (tid >> 6)) * QW;
  const int m = m0 + l15;
  const int b = m >> 16;
  const float qx = P.qc[2 * m], qy = P.qc[2 * m + 1];

  // coarse flow at query (scaled to pixel units)
  const float x8 = qx * (63.f / 511.f), y8 = qy * (47.f / 383.f);
  const float cv0 = 8.f * bilin_plane(P.coarse_flow + (b * 2 + 0) * (H8 * W8), W8, H8, x8, y8);
  const float cv1 = 8.f * bilin_plane(P.coarse_flow + (b * 2 + 1) * (H8 * W8), W8, H8, x8, y8);

  half8_t afA[8], afW[8], afB[4], hf[4];
  f32x4_t acc[16];

  // patches -> afA[0..2]  (logical cols 32kt+8g+j)
  const float* imgb = P.img + b * 3 * (IMG_H * IMG_W);
#pragma unroll
  for (int kt = 0; kt < 3; ++kt) afA[kt] = sample_patch8(imgb, qx, qy, 32 * kt + 8 * g);

  // S1: gelu(patches @ pp_w1 + pp_b1)
  gemm_acc<8, 3>(P.wpk + PW_PP1, afA, lane, acc);
  epi_af<8, 1>(acc, P.pp_b1, g, afB);
  // S2: h = t1 @ pp_w2 + pp_b2
  gemm_acc<8, 4>(P.wpk + PW_PP2, afB, lane, acc);
  epi_af<8, 0>(acc, P.pp_b2, g, hf);

  // sample f8 -> afA[0..3]; afA[4..7] = h
  const u16* ft8b = P.ft8 + b * (H8 * W8 * 128);
#pragma unroll
  for (int kt = 0; kt < 4; ++kt) afA[kt] = sample_feat8(ft8b, W8, H8, x8, y8, 32 * kt + 8 * g);
#pragma unroll
  for (int kt = 0; kt < 4; ++kt) afA[4 + kt] = hf[kt];

  // S45: [f8samp | h] @ P8CAT + fb
  gemm_acc<8, 8>(P.wpk + PW_P8CAT, afA, lane, acc);
  epi_af<8, 0>(acc, P.fb, g, afB);
  // S7: wide = gelu(. @ f1_w1 + f1_b1)
  gemm_acc<16, 4>(P.wpk + PW_F1W1, afB, lane, acc);
  epi_af<16, 1>(acc, P.f1_b1, g, afW);
  // S8 + LN1 -> h2
  gemm_acc<8, 8>(P.wpk + PW_F1W2, afW, lane, acc);
  epi_ln(acc, P.f1_b2, P.f1_ln_w, P.f1_ln_b, g, hf);

  // sample f16 -> afA[0..3]; afA[4..7] = h2
  const float x16 = qx * (31.f / 511.f), y16 = qy * (23.f / 383.f);
  const u16* ft16b = P.ft16 + b * (H16 * W16 * 128);
#pragma unroll
  for (int kt = 0; kt < 4; ++kt) afA[kt] = sample_feat8(ft16b, W16, H16, x16, y16, 32 * kt + 8 * g);
#pragma unroll
  for (int kt = 0; kt < 4; ++kt) afA[4 + kt] = hf[kt];

  // S1112
  gemm_acc<8, 8>(P.wpk + PW_P16CAT, afA, lane, acc);
  epi_af<8, 0>(acc, P.fb + 128, g, afB);
  // S14
  gemm_acc<16, 4>(P.wpk + PW_F2W1, afB, lane, acc);
  epi_af<16, 1>(acc, P.f2_b1, g, afW);
  // S15 + LN2 -> h3
  gemm_acc<8, 8>(P.wpk + PW_F2W2, afW, lane, acc);
  epi_ln(acc, P.f2_b2, P.f2_ln_w, P.f2_ln_b, g, hf);

  // S18: mi = [h3 | pe | coarse]
#pragma unroll
  for (int kt = 0; kt < 4; ++kt) afA[kt] = hf[kt];
  afA[4] = pe_frag(qx, qy, cv0, cv1, g);
  gemm_acc<8, 5>(P.wpk + PW_HW1, afA, lane, acc);
  epi_af<8, 1>(acc, P.h_b1, g, afB);

  // S19: 64 cols
  gemm_acc<4, 4>(P.wpk + PW_HW2, afB, lane, acc);

  // S19 epilogue (gelu) + S20 dot with h_w3, fused
  float d0 = 0.f, d1 = 0.f;
#pragma unroll
  for (int n = 0; n < 4; ++n) {
    const int cb = 32 * (n >> 1) + 8 * g + 4 * (n & 1);
    f32x4_t bv = *reinterpret_cast<const f32x4_t*>(P.h_b2 + cb);
#pragma unroll
    for (int r = 0; r < 4; ++r) {
      float v = geluf(acc[n][r] + bv[r]);
      f32x2_t wv = *reinterpret_cast<const f32x2_t*>(P.h_w3 + 2 * (cb + r));
      d0 += v * wv[0];
      d1 += v * wv[1];
    }
  }
  d0 += __shfl_xor(d0, 16); d1 += __shfl_xor(d1, 16);
  d0 += __shfl_xor(d0, 32); d1 += __shfl_xor(d1, 32);
  if (g == 0) {
    f32x2_t o;
    o[0] = cv0 + d0 + P.h_b3[0];
    o[1] = cv1 + d1 + P.h_b3[1];
    *reinterpret_cast<f32x2_t*>(P.out + 2 * m) = o;
  }
}

extern "C" void kernel_launch(void* const* d_in, const int* in_sizes, int n_in,
                              void* d_out, int out_size, void* d_ws, size_t ws_size,
                              hipStream_t stream) {
  u16* wp = (u16*)d_ws;
  float* fb = (float*)(wp + FB_OFF);

  PackArgs pa;
  pa.pp_w1  = (const float*)d_in[5];
  pa.pp_w2  = (const float*)d_in[7];
  pa.p8_w   = (const float*)d_in[9];
  pa.p16_w  = (const float*)d_in[11];
  pa.f1_ph_w = (const float*)d_in[13];
  pa.f1_gate = (const float*)d_in[15];
  pa.f1_w1  = (const float*)d_in[16];
  pa.f1_w2  = (const float*)d_in[18];
  pa.f2_ph_w = (const float*)d_in[22];
  pa.f2_gate = (const float*)d_in[24];
  pa.f2_w1  = (const float*)d_in[25];
  pa.f2_w2  = (const float*)d_in[27];
  pa.h_w1   = (const float*)d_in[31];
  pa.h_w2   = (const float*)d_in[33];
  pa.dst = wp;
  pack_weights<<<512, 256, 0, stream>>>(pa);
  fuse_bias<<<1, 128, 0, stream>>>((const float*)d_in[10], (const float*)d_in[14],
                                   (const float*)d_in[15], (const float*)d_in[12],
                                   (const float*)d_in[23], (const float*)d_in[24], fb);
  cvt_cl_f16<<<1024, 256, 0, stream>>>((const float*)d_in[1], wp + FT8_OFF, H8, W8);
  cvt_cl_f16<<<256, 256, 0, stream>>>((const float*)d_in[2], wp + FT16_OFF, H16, W16);

  KParams P;
  P.img = (const float*)d_in[0];
  P.coarse_flow = (const float*)d_in[3];
  P.qc = (const float*)d_in[4];
  P.wpk = wp; P.ft8 = wp + FT8_OFF; P.ft16 = wp + FT16_OFF;
  P.fb = fb;
  P.pp_b1 = (const float*)d_in[6];  P.pp_b2 = (const float*)d_in[8];
  P.f1_b1 = (const float*)d_in[17]; P.f1_b2 = (const float*)d_in[19];
  P.f1_ln_w = (const float*)d_in[20]; P.f1_ln_b = (const float*)d_in[21];
  P.f2_b1 = (const float*)d_in[26]; P.f2_b2 = (const float*)d_in[28];
  P.f2_ln_w = (const float*)d_in[29]; P.f2_ln_b = (const float*)d_in[30];
  P.h_b1 = (const float*)d_in[32]; P.h_b2 = (const float*)d_in[34];
  P.h_w3 = (const float*)d_in[35]; P.h_b3 = (const float*)d_in[36];
  P.out = (float*)d_out;

  ifd_reg<<<MTOT / (QW * WPB), NT, 0, stream>>>(P);
}

// Round 9
// 182.503 us; speedup vs baseline: 2.5778x; 2.5778x over previous
//
#include <hip/hip_runtime.h>
#include <math.h>

#define NT 512           // 8 waves
#define MB 64            // queries per block
#define MTOT 131072
#define IMG_H 384
#define IMG_W 512
#define H8 48
#define W8 64
#define H16 24
#define W16 32

#define SAB 136          // ab0/ab1 row stride (u16)
#define SHB 168          // hb row stride (u16)

typedef _Float16 half8_t __attribute__((ext_vector_type(8)));
typedef _Float16 half4_t __attribute__((ext_vector_type(4)));
typedef float f32x4_t __attribute__((ext_vector_type(4)));
typedef unsigned short u16;

// packed weight bases (in halfs) -- fragment order: ((nt*KT + kt)*64 + lane)*8 + j
// element = W[kt*32 + (lane>>4)*8 + j][nt*16 + (lane&15)]
#define PW_PP1    0
#define PW_PP2    12288
#define PW_P8CAT  28672
#define PW_P16CAT 61440
#define PW_F1W1   94208
#define PW_F1W2   126976
#define PW_F2W1   159744
#define PW_F2W2   192512
#define PW_HW1    225280
#define PW_HW2    245760
#define PW_END    253952
#define FT8_OFF   PW_END
#define FT8_CNT   (2*H8*W8*128)
#define FT16_OFF  (FT8_OFF + FT8_CNT)
#define FT16_CNT  (2*H16*W16*128)
#define FB_OFF    (FT16_OFF + FT16_CNT)   // 256 floats (fused biases), 16B aligned

__device__ __forceinline__ u16 tohalf(float v) {
  return __builtin_bit_cast(u16, (_Float16)v);
}
// tanh-form gelu: x * sigmoid(1.5957691x + 0.07135482x^3); |err vs exact erf-gelu| < 3e-3
__device__ __forceinline__ float geluf(float x) {
  float x2 = x * x;
  float t = x * fmaf(x2, 0.0713548162726f, 1.5957691216057308f);
  float e = __expf(-t);
  return x * __builtin_amdgcn_rcpf(1.0f + e);
}

// bilinear on a single [Hd][Wd] f32 plane, align_corners=True + border clamp
__device__ __forceinline__ float bilin_plane(const float* __restrict__ plane,
                                             int Wd, int Hd, float x, float y) {
  x = fminf(fmaxf(x, 0.f), (float)(Wd - 1));
  y = fminf(fmaxf(y, 0.f), (float)(Hd - 1));
  float x0f = floorf(x), y0f = floorf(y);
  int x0 = (int)x0f, y0 = (int)y0f;
  int x1 = min(x0 + 1, Wd - 1), y1 = min(y0 + 1, Hd - 1);
  float wx = x - x0f, wy = y - y0f;
  const float* r0 = plane + y0 * Wd;
  const float* r1 = plane + y1 * Wd;
  float v00 = r0[x0], v01 = r0[x1], v10 = r1[x0], v11 = r1[x1];
  float top = v00 + wx * (v01 - v00);
  float bot = v10 + wx * (v11 - v10);
  return top + wy * (bot - top);
}

// bilinear gather of 8 fp16 channels from channel-last [Hd][Wd][128] fp16
__device__ __forceinline__ void featSample(const u16* __restrict__ ft, int Wd, int Hd,
                                           float x, float y, u16* dstRow, int i16) {
  x = fminf(fmaxf(x, 0.f), (float)(Wd - 1));
  y = fminf(fmaxf(y, 0.f), (float)(Hd - 1));
  float x0f = floorf(x), y0f = floorf(y);
  int x0 = (int)x0f, y0 = (int)y0f;
  int x1 = min(x0 + 1, Wd - 1), y1 = min(y0 + 1, Hd - 1);
  float wx = x - x0f, wy = y - y0f;
  half8_t v00 = *reinterpret_cast<const half8_t*>(ft + (y0 * Wd + x0) * 128 + i16 * 8);
  half8_t v01 = *reinterpret_cast<const half8_t*>(ft + (y0 * Wd + x1) * 128 + i16 * 8);
  half8_t v10 = *reinterpret_cast<const half8_t*>(ft + (y1 * Wd + x0) * 128 + i16 * 8);
  half8_t v11 = *reinterpret_cast<const half8_t*>(ft + (y1 * Wd + x1) * 128 + i16 * 8);
  half8_t r;
#pragma unroll
  for (int j = 0; j < 8; ++j) {
    float top = (float)v00[j] + wx * ((float)v01[j] - (float)v00[j]);
    float bot = (float)v10[j] + wx * ((float)v11[j] - (float)v10[j]);
    r[j] = (_Float16)(top + wy * (bot - top));
  }
  *reinterpret_cast<half8_t*>(dstRow + i16 * 8) = r;
}

// 64-row x (NTW*8*16)-col matvec via MFMA 16x16x32 fp16, 8 waves split N,
// 4 row-fragments per wave. SWAPPED operands: lane holds 4 consecutive output
// cols (n = nt*16 + g*4 + r) for row (q = mt*16 + l15) -> half4 stores.
// ACT: 0=none, 1=gelu. NWAVES: active waves; nt = w + 8*i.
template <int NTW, int KT, int SPLITKT, int ACT, int NWAVES = 8>
__device__ __forceinline__ void mmv(
    const u16* __restrict__ wpk,
    const u16* aA, int strA, const u16* aB, int strB,
    const float* __restrict__ bias,
    u16* oA, int ostrA, u16* oB, int ostrB, int oSplitNt) {
  const int tid = threadIdx.x;
  const int lane = tid & 63;
  const int w = tid >> 6;
  const int l15 = lane & 15;
  const int g = lane >> 4;
  if (NWAVES == 8 || w < NWAVES) {
    f32x4_t acc[NTW][4];
#pragma unroll
    for (int i = 0; i < NTW; ++i)
#pragma unroll
      for (int mt = 0; mt < 4; ++mt) acc[i][mt] = (f32x4_t){0.f, 0.f, 0.f, 0.f};
#pragma unroll
    for (int kt = 0; kt < KT; ++kt) {
      const u16* ab = (kt < SPLITKT) ? (aA + kt * 32) : (aB + (kt - SPLITKT) * 32);
      const int str = (kt < SPLITKT) ? strA : strB;
      half8_t af[4];
#pragma unroll
      for (int mt = 0; mt < 4; ++mt)
        af[mt] = *reinterpret_cast<const half8_t*>(ab + (mt * 16 + l15) * str + g * 8);
#pragma unroll
      for (int i = 0; i < NTW; ++i) {
        const int nt = w + (i << 3);
        half8_t bf = *reinterpret_cast<const half8_t*>(wpk + ((nt * KT + kt) * 64 + lane) * 8);
#pragma unroll
        for (int mt = 0; mt < 4; ++mt)
          acc[i][mt] = __builtin_amdgcn_mfma_f32_16x16x32_f16(bf, af[mt], acc[i][mt], 0, 0, 0);
      }
    }
#pragma unroll
    for (int i = 0; i < NTW; ++i) {
      const int nt = w + (i << 3);
      const int colg = nt << 4;
      f32x4_t bv = *reinterpret_cast<const f32x4_t*>(bias + colg + (g << 2));
      u16* ob; int colB, ostr;
      if (nt < oSplitNt) { ob = oA; colB = colg; ostr = ostrA; }
      else { ob = oB; colB = colg - (oSplitNt << 4); ostr = ostrB; }
#pragma unroll
      for (int mt = 0; mt < 4; ++mt) {
        const int row = (mt << 4) + l15;
        half4_t hv;
#pragma unroll
        for (int r = 0; r < 4; ++r) {
          float v = acc[i][mt][r] + bv[r];
          if (ACT == 1) v = geluf(v);
          hv[r] = (_Float16)v;
        }
        *reinterpret_cast<half4_t*>(ob + row * ostr + colB + (g << 2)) = hv;
      }
    }
  }
}

// layernorm rows of src [64][SAB] -> dst [64][SHB] cols 0..127 (8 threads/row)
__device__ __forceinline__ void lnorm(const u16* src, u16* dst,
                                      const float* __restrict__ lw,
                                      const float* __restrict__ lb) {
  const int tid = threadIdx.x;
  int q = tid >> 3, s = tid & 7;
  const u16* rp = src + q * SAB + s * 16;
  float xs[16];
  float sum = 0.f, sum2 = 0.f;
#pragma unroll
  for (int c8 = 0; c8 < 2; ++c8) {
    half8_t v = *reinterpret_cast<const half8_t*>(rp + c8 * 8);
#pragma unroll
    for (int j = 0; j < 8; ++j) {
      float x = (float)v[j];
      xs[c8 * 8 + j] = x; sum += x; sum2 += x * x;
    }
  }
  sum += __shfl_xor(sum, 1); sum2 += __shfl_xor(sum2, 1);
  sum += __shfl_xor(sum, 2); sum2 += __shfl_xor(sum2, 2);
  sum += __shfl_xor(sum, 4); sum2 += __shfl_xor(sum2, 4);
  float mean = sum * 0.0078125f;
  float var = sum2 * 0.0078125f - mean * mean;
  float rstd = rsqrtf(var + 1e-5f);
  u16* op = dst + q * SHB + s * 16;
#pragma unroll
  for (int c8 = 0; c8 < 2; ++c8) {
    half8_t r;
#pragma unroll
    for (int j = 0; j < 8; ++j) {
      int c = s * 16 + c8 * 8 + j;
      r[j] = (_Float16)((xs[c8 * 8 + j] - mean) * rstd * lw[c] + lb[c]);
    }
    *reinterpret_cast<half8_t*>(op + c8 * 8) = r;
  }
}

// ---------------- prep kernels ----------------
struct PackArgs {
  const float *pp_w1, *pp_w2, *p8_w, *f1_ph_w, *f1_gate, *p16_w, *f2_ph_w, *f2_gate;
  const float *f1_w1, *f1_w2, *f2_w1, *f2_w2, *h_w1, *h_w2;
  u16* dst;
};

__global__ void pack_weights(PackArgs a) {
  const int KTs[10]   = {3, 4, 8, 8, 4, 8, 4, 8, 5, 4};
  const int Ks[10]    = {75, 128, 256, 256, 128, 256, 128, 256, 156, 128};
  const int bases[11] = {0, 12288, 28672, 61440, 94208, 126976,
                         159744, 192512, 225280, 245760, 253952};
  int stride = gridDim.x * blockDim.x;
  for (int i = blockIdx.x * blockDim.x + threadIdx.x; i < PW_END; i += stride) {
    int s = 0;
    while (i >= bases[s + 1]) ++s;
    int rem = i - bases[s];
    int e = rem & 511, lane = e >> 3, j = e & 7;
    int ntkt = rem >> 9;
    int kt = ntkt % KTs[s], nt = ntkt / KTs[s];
    int k = kt * 32 + ((lane >> 4) << 3) + j;
    int col = (nt << 4) + (lane & 15);
    float v = 0.f;
    if (k < Ks[s]) {
      switch (s) {
        case 0: v = a.pp_w1[k * 128 + col]; break;
        case 1: v = a.pp_w2[k * 128 + col]; break;
        case 2: v = (k < 128) ? a.p8_w[k * 128 + col]
                              : a.f1_ph_w[(k - 128) * 128 + col] /
                                    (1.f + expf(-a.f1_gate[col])); break;
        case 3: v = (k < 128) ? a.p16_w[k * 128 + col]
                              : a.f2_ph_w[(k - 128) * 128 + col] /
                                    (1.f + expf(-a.f2_gate[col])); break;
        case 4: v = a.f1_w1[k * 256 + col]; break;
        case 5: v = a.f1_w2[k * 128 + col]; break;
        case 6: v = a.f2_w1[k * 256 + col]; break;
        case 7: v = a.f2_w2[k * 128 + col]; break;
        case 8: v = a.h_w1[k * 128 + col]; break;
        case 9: v = a.h_w2[k * 64 + col]; break;
      }
    }
    a.dst[i] = tohalf(v);
  }
}

__global__ void fuse_bias(const float* __restrict__ p8_b, const float* __restrict__ f1_ph_b,
                          const float* __restrict__ f1_gate,
                          const float* __restrict__ p16_b, const float* __restrict__ f2_ph_b,
                          const float* __restrict__ f2_gate, float* __restrict__ fb) {
  int t = threadIdx.x;
  if (t < 128) {
    fb[t] = p8_b[t] + f1_ph_b[t] / (1.f + expf(-f1_gate[t]));
    fb[128 + t] = p16_b[t] + f2_ph_b[t] / (1.f + expf(-f2_gate[t]));
  }
}

__global__ void cvt_cl_f16(const float* __restrict__ src, u16* __restrict__ dst,
                           int Hd, int Wd) {
  int total = 2 * 128 * Hd * Wd;
  int stride = gridDim.x * blockDim.x;
  for (int i = blockIdx.x * blockDim.x + threadIdx.x; i < total; i += stride) {
    int x = i % Wd;
    int t = i / Wd;
    int y = t % Hd; t /= Hd;
    int c = t % 128;
    int b = t / 128;
    dst[((b * Hd + y) * Wd + x) * 128 + c] = tohalf(src[i]);
  }
}

// ---------------- main fused kernel ----------------
struct KParams {
  const float *img, *coarse_flow, *qc;
  const u16 *wpk, *ft8, *ft16;
  const float *fb;   // fused biases: [0..127]=p8+sig*f1_ph, [128..255]=p16+sig*f2_ph
  const float *pp_b1, *pp_b2;
  const float *f1_b1, *f1_b2, *f1_ln_w, *f1_ln_b;
  const float *f2_b1, *f2_b2, *f2_ln_w, *f2_ln_b;
  const float *h_b1, *h_b2, *h_w3, *h_b3;
  float* out;
};

__global__ __launch_bounds__(NT, 2) void ifd_mfma(KParams P) {
  __shared__ __align__(16) u16 smem[2 * (MB * SAB) + MB * SHB];
  __shared__ float qcL[2 * MB];
  __shared__ float cb[2 * MB];
  u16* ab0 = smem;
  u16* ab1 = smem + MB * SAB;
  u16* hb  = smem + 2 * MB * SAB;

  const int tid = threadIdx.x;
  const int m0 = blockIdx.x * MB;

  // P0a: query coords to LDS
  if (tid < 2 * MB) qcL[tid] = P.qc[m0 * 2 + tid];
  __syncthreads();

  // P0b: patches -> ab0 cols 0..95; pe/coarse -> hb cols 128..167 + cb
  for (int i = tid; i < MB * 96; i += NT) {
    int q = i / 96, c = i - q * 96;
    u16 val = 0;
    if (c < 75) {
      int m = m0 + q, b = m >> 16;
      float qx = qcL[2 * q], qy = qcL[2 * q + 1];
      int p = c / 3, ch = c - p * 3;
      int iy = p / 5, ix = p - iy * 5;
      const float* plane = P.img + (b * 3 + ch) * (IMG_H * IMG_W);
      val = tohalf(bilin_plane(plane, IMG_W, IMG_H,
                               qx + (float)(ix - 2), qy + (float)(iy - 2)));
    }
    ab0[q * SAB + c] = val;
  }
  for (int i = tid; i < MB * 40; i += NT) {
    int q = i / 40, c = i - q * 40;
    int m = m0 + q, b = m >> 16;
    float qx = qcL[2 * q], qy = qcL[2 * q + 1];
    float val = 0.f;
    if (c < 26) {
      float qx8 = qx * 0.125f, qy8 = qy * 0.125f;
      float lx = (qx8 - rintf(qx8)) * 2.f, ly = (qy8 - rintf(qy8)) * 2.f;
      if (c < 2) val = c ? ly : lx;
      else {
        int k = c - 2;
        int dim = k / 12, tt = k - dim * 12;
        int band = tt % 6, iscos = tt / 6;
        float loc = dim ? ly : lx;
        float ang = loc * 3.14159265358979323846f * (float)(1 << band);
        val = iscos ? __cosf(ang) : __sinf(ang);
      }
    } else if (c < 28) {
      int o = c - 26;
      float x8 = qx * (63.f / 511.f), y8 = qy * (47.f / 383.f);
      float cv = 8.f * bilin_plane(P.coarse_flow + (b * 2 + o) * (H8 * W8), W8, H8, x8, y8);
      cb[q * 2 + o] = cv;
      val = cv;
    }
    hb[q * SHB + 128 + c] = tohalf(val);
  }
  __syncthreads();

  // S1: ab1 = gelu(patches @ pp_w1 + pp_b1)
  mmv<1, 3, 3, 1>(P.wpk + PW_PP1, ab0, SAB, ab0, SAB, P.pp_b1,
                  ab1, SAB, ab1, SAB, 16);
  __syncthreads();
  // S2: hb(h) = ab1 @ pp_w2 + pp_b2 ; sample f8 -> ab0
  mmv<1, 4, 4, 0>(P.wpk + PW_PP2, ab1, SAB, ab1, SAB, P.pp_b2,
                  hb, SHB, hb, SHB, 16);
  for (int i = tid; i < MB * 16; i += NT) {
    int q = i >> 4, i16 = i & 15;
    int m = m0 + q, b = m >> 16;
    float x = qcL[2 * q] * (63.f / 511.f), y = qcL[2 * q + 1] * (47.f / 383.f);
    featSample(P.ft8 + b * (H8 * W8 * 128), W8, H8, x, y, ab0 + q * SAB, i16);
  }
  __syncthreads();
  // S45: ab1 = [samp8 | h] @ P8CAT + fb8  (= f8 + sig(g1)*(h@ph_w+ph_b))
  mmv<1, 8, 4, 0>(P.wpk + PW_P8CAT, ab0, SAB, hb, SHB, P.fb,
                  ab1, SAB, ab1, SAB, 16);
  __syncthreads();
  // S7: wide = gelu(ab1 @ f1_w1 + f1_b1): cols 0-127 -> ab0, 128-255 -> hb(0..127)
  mmv<2, 4, 4, 1>(P.wpk + PW_F1W1, ab1, SAB, ab1, SAB, P.f1_b1,
                  ab0, SAB, hb, SHB, 8);
  __syncthreads();
  // S8: ab1 = wide @ f1_w2 + f1_b2 (K=256)
  mmv<1, 8, 4, 0>(P.wpk + PW_F1W2, ab0, SAB, hb, SHB, P.f1_b2,
                  ab1, SAB, ab1, SAB, 16);
  __syncthreads();
  // LN1 -> hb ; sample f16 -> ab0
  lnorm(ab1, hb, P.f1_ln_w, P.f1_ln_b);
  for (int i = tid; i < MB * 16; i += NT) {
    int q = i >> 4, i16 = i & 15;
    int m = m0 + q, b = m >> 16;
    float x = qcL[2 * q] * (31.f / 511.f), y = qcL[2 * q + 1] * (23.f / 383.f);
    featSample(P.ft16 + b * (H16 * W16 * 128), W16, H16, x, y, ab0 + q * SAB, i16);
  }
  __syncthreads();
  // S1112: ab1 = [samp16 | h'] @ P16CAT + fb16
  mmv<1, 8, 4, 0>(P.wpk + PW_P16CAT, ab0, SAB, hb, SHB, P.fb + 128,
                  ab1, SAB, ab1, SAB, 16);
  __syncthreads();
  // S14: wide2 = gelu(ab1 @ f2_w1 + f2_b1)
  mmv<2, 4, 4, 1>(P.wpk + PW_F2W1, ab1, SAB, ab1, SAB, P.f2_b1,
                  ab0, SAB, hb, SHB, 8);
  __syncthreads();
  // S15: ab1 = wide2 @ f2_w2 + f2_b2
  mmv<1, 8, 4, 0>(P.wpk + PW_F2W2, ab0, SAB, hb, SHB, P.f2_b2,
                  ab1, SAB, ab1, SAB, 16);
  __syncthreads();
  // LN2 -> hb
  lnorm(ab1, hb, P.f2_ln_w, P.f2_ln_b);
  __syncthreads();
  // S18: ab1 = gelu(mi @ h_w1 + h_b1)  (K=160: hb = h | pe | coarse | 0)
  mmv<1, 5, 5, 1>(P.wpk + PW_HW1, hb, SHB, hb, SHB, P.h_b1,
                  ab1, SAB, ab1, SAB, 16);
  __syncthreads();
  // S19: ab0 cols 0..63 = gelu(ab1 @ h_w2 + h_b2)  (waves 0-3)
  mmv<1, 4, 4, 1, 4>(P.wpk + PW_HW2, ab1, SAB, ab1, SAB, P.h_b2,
                     ab0, SAB, ab0, SAB, 16);
  __syncthreads();
  // S20: out = coarse + (g @ h_w3 + h_b3)
  if (tid < 2 * MB) {
    int q = tid >> 1, o = tid & 1;
    float acc = P.h_b3[o];
    const u16* rp = ab0 + q * SAB;
#pragma unroll
    for (int c8 = 0; c8 < 8; ++c8) {
      half8_t v = *reinterpret_cast<const half8_t*>(rp + c8 * 8);
#pragma unroll
      for (int j = 0; j < 8; ++j) acc += (float)v[j] * P.h_w3[(c8 * 8 + j) * 2 + o];
    }
    P.out[(m0 + q) * 2 + o] = cb[q * 2 + o] + acc;
  }
}

extern "C" void kernel_launch(void* const* d_in, const int* in_sizes, int n_in,
                              void* d_out, int out_size, void* d_ws, size_t ws_size,
                              hipStream_t stream) {
  u16* wp = (u16*)d_ws;
  float* fb = (float*)(wp + FB_OFF);

  PackArgs pa;
  pa.pp_w1  = (const float*)d_in[5];
  pa.pp_w2  = (const float*)d_in[7];
  pa.p8_w   = (const float*)d_in[9];
  pa.p16_w  = (const float*)d_in[11];
  pa.f1_ph_w = (const float*)d_in[13];
  pa.f1_gate = (const float*)d_in[15];
  pa.f1_w1  = (const float*)d_in[16];
  pa.f1_w2  = (const float*)d_in[18];
  pa.f2_ph_w = (const float*)d_in[22];
  pa.f2_gate = (const float*)d_in[24];
  pa.f2_w1  = (const float*)d_in[25];
  pa.f2_w2  = (const float*)d_in[27];
  pa.h_w1   = (const float*)d_in[31];
  pa.h_w2   = (const float*)d_in[33];
  pa.dst = wp;
  pack_weights<<<512, 256, 0, stream>>>(pa);
  fuse_bias<<<1, 128, 0, stream>>>((const float*)d_in[10], (const float*)d_in[14],
                                   (const float*)d_in[15], (const float*)d_in[12],
                                   (const float*)d_in[23], (const float*)d_in[24], fb);
  cvt_cl_f16<<<1024, 256, 0, stream>>>((const float*)d_in[1], wp + FT8_OFF, H8, W8);
  cvt_cl_f16<<<256, 256, 0, stream>>>((const float*)d_in[2], wp + FT16_OFF, H16, W16);

  KParams P;
  P.img = (const float*)d_in[0];
  P.coarse_flow = (const float*)d_in[3];
  P.qc = (const float*)d_in[4];
  P.wpk = wp; P.ft8 = wp + FT8_OFF; P.ft16 = wp + FT16_OFF;
  P.fb = fb;
  P.pp_b1 = (const float*)d_in[6];  P.pp_b2 = (const float*)d_in[8];
  P.f1_b1 = (const float*)d_in[17]; P.f1_b2 = (const float*)d_in[19];
  P.f1_ln_w = (const float*)d_in[20]; P.f1_ln_b = (const float*)d_in[21];
  P.f2_b1 = (const float*)d_in[26]; P.f2_b2 = (const float*)d_in[28];
  P.f2_ln_w = (const float*)d_in[29]; P.f2_ln_b = (const float*)d_in[30];
  P.h_b1 = (const float*)d_in[32]; P.h_b2 = (const float*)d_in[34];
  P.h_w3 = (const float*)d_in[35]; P.h_b3 = (const float*)d_in[36];
  P.out = (float*)d_out;

  ifd_mfma<<<MTOT / MB, NT, 0, stream>>>(P);
}